// Round 1
// baseline (282.795 us; speedup 1.0000x reference)
//
#include <hip/hip_runtime.h>

// Problem constants (from reference): B=32, C_IN=64, C_OUT=128, K=3, H=W=128
#define BATCH 32
#define CIN   64
#define COUT  128
#define HW    128
#define OW    126          // H-K+1

// ---- Kernel 1: xs[c,h,w] = sum_b x[b,c,h,w], float4-vectorized ----
__global__ void k_bsum(const float* __restrict__ x, float* __restrict__ xs) {
    const int i = blockIdx.x * blockDim.x + threadIdx.x;   // over 262144 float4s
    const float4* __restrict__ x4 = (const float4*)x;
    const int stride4 = CIN * HW * HW / 4;                 // 262144 float4 per batch
    float4 acc = x4[i];
    #pragma unroll
    for (int b = 1; b < BATCH; ++b) {
        float4 v = x4[(size_t)b * stride4 + i];
        acc.x += v.x; acc.y += v.y; acc.z += v.z; acc.w += v.w;
    }
    ((float4*)xs)[i] = acc;
}

// ---- Kernel 2: conv(xs, w) + bias, broadcast-written to all 32 batch rows ----
// Grid: blockIdx.x = spatial tile (4x4 tiles of 32x32 output), blockIdx.y = oc group (8 oc each)
// Block: 256 threads; thread (ty 0..31, tx 0..7); each thread: 1 row x 4 cols x 8 oc.
#define OCT    8           // out channels per block
#define ICC    8           // input-channel chunk staged in LDS
#define TR     34          // input tile rows/cols (32 + K - 1)
#define TPITCH 36          // padded pitch (keeps 16B alignment, floats)

__global__ __launch_bounds__(256, 1) void k_conv(const float* __restrict__ xs,
                                                 const float* __restrict__ w,
                                                 const float* __restrict__ bias,
                                                 float* __restrict__ out) {
    __shared__ float lw[CIN * 9 * OCT];        // 4608 f: layout [ic][ky][kx][oc]
    __shared__ float lx[ICC * TR * TPITCH];    // 9792 f: layout [ic][r][c], pitch 36

    const int tid  = threadIdx.x;
    const int tile = blockIdx.x;               // 0..15
    const int ocg  = blockIdx.y;               // 0..15
    const int row0 = (tile >> 2) * 32;
    const int col0 = (tile & 3) * 32;
    const int oc0  = ocg * OCT;

    // Stage ALL weights for this oc group: global [oc][ic*9+t] -> lds [(ic*9+t)*8+o]
    for (int s = tid; s < CIN * 9 * OCT; s += 256) {
        const int o = s & 7;
        const int t = s >> 3;                  // ic*9 + ky*3 + kx
        lw[s] = w[(oc0 + o) * (CIN * 9) + t];
    }

    const int ty   = tid >> 3;                 // 0..31
    const int tx   = tid & 7;                  // 0..7
    const int orow = row0 + ty;
    const int ocol = col0 + tx * 4;

    float acc[OCT][4] = {};

    for (int ic0 = 0; ic0 < CIN; ic0 += ICC) {
        __syncthreads();                       // also covers lw staging on first pass
        // Stage input tile for this ic chunk (clamped reads at borders)
        for (int s = tid; s < ICC * TR * TR; s += 256) {
            const int c  = s % TR;
            const int t  = s / TR;
            const int r  = t % TR;
            const int ic = t / TR;
            const int gr = row0 + r, gc = col0 + c;
            float v = 0.f;
            if (gr < HW && gc < HW)
                v = xs[((ic0 + ic) * HW + gr) * HW + gc];
            lx[(ic * TR + r) * TPITCH + c] = v;
        }
        __syncthreads();

        for (int ic = 0; ic < ICC; ++ic) {
            #pragma unroll
            for (int ky = 0; ky < 3; ++ky) {
                const float* xr = &lx[(ic * TR + ty + ky) * TPITCH + tx * 4];
                const float4 xa = *(const float4*)xr;        // cols 0..3 (16B aligned)
                const float2 xb = *(const float2*)(xr + 4);  // cols 4..5
                const float xv[6] = {xa.x, xa.y, xa.z, xa.w, xb.x, xb.y};
                const float* wp = &lw[((ic0 + ic) * 9 + ky * 3) * 8];
                #pragma unroll
                for (int kx = 0; kx < 3; ++kx) {
                    #pragma unroll
                    for (int o = 0; o < OCT; ++o) {
                        const float wv = wp[kx * 8 + o];
                        #pragma unroll
                        for (int p = 0; p < 4; ++p)
                            acc[o][p] = fmaf(wv, xv[kx + p], acc[o][p]);
                    }
                }
            }
        }
    }

    // Bias
    #pragma unroll
    for (int o = 0; o < OCT; ++o) {
        const float bv = bias[oc0 + o];
        #pragma unroll
        for (int p = 0; p < 4; ++p) acc[o][p] += bv;
    }

    // Broadcast write to all 32 batch rows (row pitch 126f = 504B -> only 8B aligned, use float2)
    if (orow < OW) {
        const int nv = OW - ocol;              // >= 2 always (max ocol = 124)
        #pragma unroll 4
        for (int b = 0; b < BATCH; ++b) {
            #pragma unroll
            for (int o = 0; o < OCT; ++o) {
                float* op = &out[(((size_t)b * COUT + oc0 + o) * OW + orow) * OW + ocol];
                if (nv >= 4) {
                    ((float2*)op)[0] = make_float2(acc[o][0], acc[o][1]);
                    ((float2*)op)[1] = make_float2(acc[o][2], acc[o][3]);
                } else {
                    for (int j = 0; j < nv; ++j) op[j] = acc[o][j];
                }
            }
        }
    }
}

extern "C" void kernel_launch(void* const* d_in, const int* in_sizes, int n_in,
                              void* d_out, int out_size, void* d_ws, size_t ws_size,
                              hipStream_t stream) {
    const float* x    = (const float*)d_in[0];   // [32,64,128,128]
    const float* w    = (const float*)d_in[1];   // [128,64,3,3]
    const float* bias = (const float*)d_in[2];   // [128,1,1]
    float* out = (float*)d_out;                  // [32,128,126,126]
    float* xs  = (float*)d_ws;                   // [64,128,128] scratch (4 MB)

    k_bsum<<<dim3(CIN * HW * HW / 4 / 256), dim3(256), 0, stream>>>(x, xs);
    k_conv<<<dim3(16, 16), dim3(256), 0, stream>>>(xs, w, bias, out);
}

// Round 2
// 239.055 us; speedup vs baseline: 1.1830x; 1.1830x over previous
//
#include <hip/hip_runtime.h>

// Problem constants: B=32, C_IN=64, C_OUT=128, K=3, H=W=128
#define BATCH 32
#define CIN   64
#define COUT  128
#define HW    128
#define OW    126            // H-K+1
#define IMG4  508032         // floats per batch-image of out / 4  (128*126*126/4)

// ---- Kernel 1: xs[c,h,w] = sum_b x[b,c,h,w], float4, 2 independent acc chains ----
__global__ void k_bsum(const float* __restrict__ x, float* __restrict__ xs) {
    const int i = blockIdx.x * blockDim.x + threadIdx.x;   // over 262144 float4s
    const float4* __restrict__ x4 = (const float4*)x;
    const size_t s4 = CIN * HW * HW / 4;                   // 262144 float4 per batch
    float4 a0 = x4[i];
    float4 a1 = x4[s4 + i];
    #pragma unroll
    for (int b = 2; b < BATCH; b += 2) {
        float4 v0 = x4[(size_t)b * s4 + i];
        float4 v1 = x4[(size_t)(b + 1) * s4 + i];
        a0.x += v0.x; a0.y += v0.y; a0.z += v0.z; a0.w += v0.w;
        a1.x += v1.x; a1.y += v1.y; a1.z += v1.z; a1.w += v1.w;
    }
    a0.x += a1.x; a0.y += a1.y; a0.z += a1.z; a0.w += a1.w;
    ((float4*)xs)[i] = a0;
}

// ---- Kernel 2: conv(xs, w) + bias -> out batch 0 ONLY (8.1 MB) ----
#define OCT    8           // out channels per block
#define ICC    8           // input-channel chunk staged in LDS
#define TR     34          // input tile rows/cols (32 + K - 1)
#define TPITCH 36          // padded pitch (keeps 16B alignment)

__global__ __launch_bounds__(256, 1) void k_conv(const float* __restrict__ xs,
                                                 const float* __restrict__ w,
                                                 const float* __restrict__ bias,
                                                 float* __restrict__ out) {
    __shared__ float lw[CIN * 9 * OCT];        // [ic][ky][kx][oc]
    __shared__ float lx[ICC * TR * TPITCH];    // [ic][r][c]

    const int tid  = threadIdx.x;
    const int tile = blockIdx.x;               // 0..15
    const int ocg  = blockIdx.y;               // 0..15
    const int row0 = (tile >> 2) * 32;
    const int col0 = (tile & 3) * 32;
    const int oc0  = ocg * OCT;

    for (int s = tid; s < CIN * 9 * OCT; s += 256) {
        const int o = s & 7;
        const int t = s >> 3;                  // ic*9 + ky*3 + kx
        lw[s] = w[(oc0 + o) * (CIN * 9) + t];
    }

    const int ty   = tid >> 3;                 // 0..31
    const int tx   = tid & 7;                  // 0..7
    const int orow = row0 + ty;
    const int ocol = col0 + tx * 4;

    float acc[OCT][4] = {};

    for (int ic0 = 0; ic0 < CIN; ic0 += ICC) {
        __syncthreads();
        for (int s = tid; s < ICC * TR * TR; s += 256) {
            const int c  = s % TR;
            const int t  = s / TR;
            const int r  = t % TR;
            const int ic = t / TR;
            const int gr = row0 + r, gc = col0 + c;
            float v = 0.f;
            if (gr < HW && gc < HW)
                v = xs[((ic0 + ic) * HW + gr) * HW + gc];
            lx[(ic * TR + r) * TPITCH + c] = v;
        }
        __syncthreads();

        for (int ic = 0; ic < ICC; ++ic) {
            #pragma unroll
            for (int ky = 0; ky < 3; ++ky) {
                const float* xr = &lx[(ic * TR + ty + ky) * TPITCH + tx * 4];
                const float4 xa = *(const float4*)xr;
                const float2 xb = *(const float2*)(xr + 4);
                const float xv[6] = {xa.x, xa.y, xa.z, xa.w, xb.x, xb.y};
                const float* wp = &lw[((ic0 + ic) * 9 + ky * 3) * 8];
                #pragma unroll
                for (int kx = 0; kx < 3; ++kx) {
                    #pragma unroll
                    for (int o = 0; o < OCT; ++o) {
                        const float wv = wp[kx * 8 + o];
                        #pragma unroll
                        for (int p = 0; p < 4; ++p)
                            acc[o][p] = fmaf(wv, xv[kx + p], acc[o][p]);
                    }
                }
            }
        }
    }

    #pragma unroll
    for (int o = 0; o < OCT; ++o) {
        const float bv = bias[oc0 + o];
        #pragma unroll
        for (int p = 0; p < 4; ++p) acc[o][p] += bv;
    }

    // Write batch 0 only (row pitch 126f -> 8B aligned, use float2)
    if (orow < OW) {
        const int nv = OW - ocol;              // >= 2 always
        #pragma unroll
        for (int o = 0; o < OCT; ++o) {
            float* op = &out[((size_t)(oc0 + o) * OW + orow) * OW + ocol];
            if (nv >= 4) {
                ((float2*)op)[0] = make_float2(acc[o][0], acc[o][1]);
                ((float2*)op)[1] = make_float2(acc[o][2], acc[o][3]);
            } else {
                op[0] = acc[o][0]; op[1] = acc[o][1];
            }
        }
    }
}

// ---- Kernel 3: broadcast out[0] -> out[1..31], dense aligned float4 copy ----
// grid (31, 993): blockIdx.x = dst batch - 1 (fastest varying -> concurrent
// blocks read the same src region -> L2 hits), blockIdx.y = chunk of 512 float4.
__global__ void k_bcast(float* __restrict__ out) {
    const size_t dstBase = (size_t)(blockIdx.x + 1) * IMG4;
    const int r0 = blockIdx.y * 512 + threadIdx.x;
    float4* __restrict__ o4 = (float4*)out;
    #pragma unroll
    for (int j = 0; j < 2; ++j) {
        const int r = r0 + j * 256;
        if (r < IMG4) o4[dstBase + r] = o4[r];
    }
}

extern "C" void kernel_launch(void* const* d_in, const int* in_sizes, int n_in,
                              void* d_out, int out_size, void* d_ws, size_t ws_size,
                              hipStream_t stream) {
    const float* x    = (const float*)d_in[0];   // [32,64,128,128]
    const float* w    = (const float*)d_in[1];   // [128,64,3,3]
    const float* bias = (const float*)d_in[2];   // [128,1,1]
    float* out = (float*)d_out;                  // [32,128,126,126]
    float* xs  = (float*)d_ws;                   // [64,128,128] scratch (4 MB)

    k_bsum<<<dim3(CIN * HW * HW / 4 / 256), dim3(256), 0, stream>>>(x, xs);
    k_conv<<<dim3(16, 16), dim3(256), 0, stream>>>(xs, w, bias, out);
    k_bcast<<<dim3(BATCH - 1, (IMG4 + 511) / 512), dim3(256), 0, stream>>>(out);
}

// Round 3
// 162.604 us; speedup vs baseline: 1.7392x; 1.4702x over previous
//
#include <hip/hip_runtime.h>

// Problem constants: B=32, C_IN=64, C_OUT=128, K=3, H=W=128
#define BATCH 32
#define CIN   64
#define COUT  128
#define HW    128
#define OW    126            // H-K+1
#define IMG4  508032         // floats per batch-image of out / 4  (128*126*126/4)

// ---- Kernel 1: xs[c,h,w] = sum_b x[b,c,h,w], float4, 2 independent acc chains ----
__global__ void k_bsum(const float* __restrict__ x, float* __restrict__ xs) {
    const int i = blockIdx.x * blockDim.x + threadIdx.x;   // over 262144 float4s
    const float4* __restrict__ x4 = (const float4*)x;
    const size_t s4 = CIN * HW * HW / 4;                   // 262144 float4 per batch
    float4 a0 = x4[i];
    float4 a1 = x4[s4 + i];
    #pragma unroll
    for (int b = 2; b < BATCH; b += 2) {
        float4 v0 = x4[(size_t)b * s4 + i];
        float4 v1 = x4[(size_t)(b + 1) * s4 + i];
        a0.x += v0.x; a0.y += v0.y; a0.z += v0.z; a0.w += v0.w;
        a1.x += v1.x; a1.y += v1.y; a1.z += v1.z; a1.w += v1.w;
    }
    a0.x += a1.x; a0.y += a1.y; a0.z += a1.z; a0.w += a1.w;
    ((float4*)xs)[i] = a0;
}

// ---- Kernel 2: conv(xs, w) + bias -> out batch 0 ONLY ----
// Tile: 16 rows x 32 cols of output, 8 out-channels per block.
// Grid: x = 32 spatial tiles (8 row-tiles x 4 col-tiles), y = 16 oc groups -> 512 blocks.
// Thread (256): tx=tid&7 (4 cols each), ty=(tid>>3)&15 (row), og=tid>>7 (oc half of 4).
#define OCT    8           // out channels per block
#define ICC    8           // input-channel chunk staged in LDS
#define TROWS  18          // input tile rows (16 + 2)
#define TPITCH 36          // LDS row pitch in floats (34 cols + pad, 16B-aligned steps)

__global__ __launch_bounds__(256, 2) void k_conv(const float* __restrict__ xs,
                                                 const float* __restrict__ w,
                                                 const float* __restrict__ bias,
                                                 float* __restrict__ out) {
    __shared__ float lw[CIN * 9 * OCT];           // [(ic*9 + ky*3 + kx)*8 + o] : 18.4 KB
    __shared__ float lx[ICC * TROWS * TPITCH];    // [ic][r][c] pitch 36       : 20.7 KB

    const int tid  = threadIdx.x;
    const int tile = blockIdx.x;                  // 0..31
    const int ocg  = blockIdx.y;                  // 0..15
    const int row0 = (tile >> 2) * 16;            // 0,16,...,112
    const int col0 = (tile & 3) * 32;             // 0,32,64,96
    const int oc0  = ocg * OCT;

    // Stage all weights for this oc group: [oc][ic*9+t] -> [(ic*9+t)*8 + o]
    for (int s = tid; s < CIN * 9 * OCT; s += 256) {
        const int o = s & 7;
        const int t = s >> 3;
        lw[s] = w[(oc0 + o) * (CIN * 9) + t];
    }

    const int tx = tid & 7;
    const int ty = (tid >> 3) & 15;
    const int og = tid >> 7;                      // 0/1: which 4 of the 8 oc

    float acc[4][4] = {};                         // [oc][px]

    for (int ic0 = 0; ic0 < CIN; ic0 += ICC) {
        __syncthreads();                          // covers lw staging on first pass
        // Stage input tile: one LDS row (34 cols) per thread, threads 0..143
        if (tid < ICC * TROWS) {
            const int ic = tid / TROWS;
            const int r  = tid % TROWS;
            const int gr = row0 + r;
            float* dst = &lx[(ic * TROWS + r) * TPITCH];
            if (gr < HW) {
                const float* src = &xs[((ic0 + ic) * HW + gr) * HW + col0];
                #pragma unroll
                for (int k = 0; k < 8; ++k)
                    *(float4*)(dst + 4 * k) = *(const float4*)(src + 4 * k);
                float2 t = make_float2(0.f, 0.f);
                if (col0 + 32 < HW) t = *(const float2*)(src + 32);
                *(float2*)(dst + 32) = t;
            } else {
                #pragma unroll
                for (int k = 0; k < 8; ++k)
                    *(float4*)(dst + 4 * k) = make_float4(0.f, 0.f, 0.f, 0.f);
                *(float2*)(dst + 32) = make_float2(0.f, 0.f);
            }
        }
        __syncthreads();

        for (int ic = 0; ic < ICC; ++ic) {
            const int icg = ic0 + ic;
            #pragma unroll
            for (int ky = 0; ky < 3; ++ky) {
                const float* xr = &lx[(ic * TROWS + ty + ky) * TPITCH + tx * 4];
                const float4 xa = *(const float4*)xr;         // cols 0..3 (16B aligned)
                const float2 xb = *(const float2*)(xr + 4);   // cols 4..5
                const float xv[6] = {xa.x, xa.y, xa.z, xa.w, xb.x, xb.y};
                const float* wb = &lw[(icg * 9 + ky * 3) * 8 + og * 4];
                #pragma unroll
                for (int kx = 0; kx < 3; ++kx) {
                    const float4 wv = *(const float4*)(wb + kx * 8);  // 4 oc, broadcast
                    const float wf[4] = {wv.x, wv.y, wv.z, wv.w};
                    #pragma unroll
                    for (int o = 0; o < 4; ++o)
                        #pragma unroll
                        for (int p = 0; p < 4; ++p)
                            acc[o][p] = fmaf(wf[o], xv[kx + p], acc[o][p]);
                }
            }
        }
    }

    // Bias + write batch 0 only
    const int orow = row0 + ty;
    const int ocol = col0 + tx * 4;
    if (orow < OW) {
        const int nv = OW - ocol;                 // 4.. or 2 at the right edge
        #pragma unroll
        for (int o = 0; o < 4; ++o) {
            const int oc = oc0 + og * 4 + o;
            const float bv = bias[oc];
            float r0 = acc[o][0] + bv, r1 = acc[o][1] + bv;
            float r2 = acc[o][2] + bv, r3 = acc[o][3] + bv;
            float* op = &out[((size_t)oc * OW + orow) * OW + ocol];
            if (nv >= 4) {
                ((float2*)op)[0] = make_float2(r0, r1);
                ((float2*)op)[1] = make_float2(r2, r3);
            } else {
                ((float2*)op)[0] = make_float2(r0, r1);
            }
        }
    }
}

// ---- Kernel 3: broadcast out[0] -> out[1..31], dense aligned float4 copy ----
__global__ void k_bcast(float* __restrict__ out) {
    const size_t dstBase = (size_t)(blockIdx.x + 1) * IMG4;
    const int r0 = blockIdx.y * 512 + threadIdx.x;
    float4* __restrict__ o4 = (float4*)out;
    #pragma unroll
    for (int j = 0; j < 2; ++j) {
        const int r = r0 + j * 256;
        if (r < IMG4) o4[dstBase + r] = o4[r];
    }
}

extern "C" void kernel_launch(void* const* d_in, const int* in_sizes, int n_in,
                              void* d_out, int out_size, void* d_ws, size_t ws_size,
                              hipStream_t stream) {
    const float* x    = (const float*)d_in[0];   // [32,64,128,128]
    const float* w    = (const float*)d_in[1];   // [128,64,3,3]
    const float* bias = (const float*)d_in[2];   // [128,1,1]
    float* out = (float*)d_out;                  // [32,128,126,126]
    float* xs  = (float*)d_ws;                   // [64,128,128] scratch (4 MB)

    k_bsum<<<dim3(CIN * HW * HW / 4 / 256), dim3(256), 0, stream>>>(x, xs);
    k_conv<<<dim3(32, 16), dim3(256), 0, stream>>>(xs, w, bias, out);
    k_bcast<<<dim3(BATCH - 1, (IMG4 + 511) / 512), dim3(256), 0, stream>>>(out);
}

// Round 5
// 155.576 us; speedup vs baseline: 1.8177x; 1.0452x over previous
//
#include <hip/hip_runtime.h>

// Problem constants: B=32, C_IN=64, C_OUT=128, K=3, H=W=128
#define BATCH 32
#define CIN   64
#define COUT  128
#define HW    128
#define OW    126            // H-K+1
#define IMG4  508032         // float4s per batch-image of out (128*126*126/4)

// native clang vector type — accepted by __builtin_nontemporal_*
typedef float f4 __attribute__((ext_vector_type(4)));

// ---- Kernel 1: xs[c,h,w] = sum_b x[b,c,h,w]; f4, 4 chains, nt loads ----
__global__ __launch_bounds__(256) void k_bsum(const float* __restrict__ x,
                                              float* __restrict__ xs) {
    const int i = blockIdx.x * blockDim.x + threadIdx.x;   // over 262144 f4s
    const f4* __restrict__ x4 = (const f4*)x;
    const size_t s4 = CIN * HW * HW / 4;                   // 262144 f4 per batch
    f4 a0 = __builtin_nontemporal_load(&x4[i]);
    f4 a1 = __builtin_nontemporal_load(&x4[s4 + i]);
    f4 a2 = __builtin_nontemporal_load(&x4[2 * s4 + i]);
    f4 a3 = __builtin_nontemporal_load(&x4[3 * s4 + i]);
    #pragma unroll
    for (int b = 4; b < BATCH; b += 4) {
        a0 += __builtin_nontemporal_load(&x4[(size_t)b * s4 + i]);
        a1 += __builtin_nontemporal_load(&x4[(size_t)(b + 1) * s4 + i]);
        a2 += __builtin_nontemporal_load(&x4[(size_t)(b + 2) * s4 + i]);
        a3 += __builtin_nontemporal_load(&x4[(size_t)(b + 3) * s4 + i]);
    }
    ((f4*)xs)[i] = (a0 + a1) + (a2 + a3);
}

// ---- Kernel 2: conv(xs, w) + bias -> out batch 0 ONLY ----
// Tile: 8 output rows x 32 cols, 8 oc per block.
// Grid: x = 64 spatial tiles (16 row-tiles x 4 col-tiles), y = 16 oc groups -> 1024 blocks (4/CU).
// Thread (256): tx=tid&7 (4 cols), ty=(tid>>3)&7 (row), og=tid>>6 (2 oc each).
#define OCT    8           // out channels per block
#define ICC    8           // input-channel chunk staged in LDS
#define TROWS  10          // input tile rows (8 + 2)
#define TPITCH 36          // LDS row pitch in floats (34 cols + pad)

__global__ __launch_bounds__(256, 4) void k_conv(const float* __restrict__ xs,
                                                 const float* __restrict__ w,
                                                 const float* __restrict__ bias,
                                                 float* __restrict__ out) {
    __shared__ float lw[CIN * 9 * OCT];           // [(ic*9 + ky*3 + kx)*8 + o] : 18.4 KB
    __shared__ float lx[ICC * TROWS * TPITCH];    // [ic][r][c] pitch 36        : 11.5 KB

    const int tid  = threadIdx.x;
    const int tile = blockIdx.x;                  // 0..63
    const int ocg  = blockIdx.y;                  // 0..15
    const int row0 = (tile >> 2) * 8;             // 0,8,...,120
    const int col0 = (tile & 3) * 32;             // 0,32,64,96
    const int oc0  = ocg * OCT;

    // Stage all weights for this oc group: [oc][ic*9+t] -> [(ic*9+t)*8 + o]
    for (int s = tid; s < CIN * 9 * OCT; s += 256) {
        const int o = s & 7;
        const int t = s >> 3;
        lw[s] = w[(oc0 + o) * (CIN * 9) + t];
    }

    const int tx = tid & 7;
    const int ty = (tid >> 3) & 7;
    const int og = tid >> 6;                      // 0..3: which 2 of the 8 oc

    float acc[2][4] = {};                         // [oc][px]

    for (int ic0 = 0; ic0 < CIN; ic0 += ICC) {
        __syncthreads();                          // covers lw staging on first pass
        // Stage input tile: one LDS row (34 cols) per thread, threads 0..79
        if (tid < ICC * TROWS) {
            const int ic = tid / TROWS;
            const int r  = tid % TROWS;
            const int gr = row0 + r;
            float* dst = &lx[(ic * TROWS + r) * TPITCH];
            if (gr < HW) {
                const float* src = &xs[((ic0 + ic) * HW + gr) * HW + col0];
                #pragma unroll
                for (int k = 0; k < 8; ++k)
                    *(float4*)(dst + 4 * k) = *(const float4*)(src + 4 * k);
                float2 t = make_float2(0.f, 0.f);
                if (col0 + 32 < HW) t = *(const float2*)(src + 32);
                *(float2*)(dst + 32) = t;
            } else {
                #pragma unroll
                for (int k = 0; k < 8; ++k)
                    *(float4*)(dst + 4 * k) = make_float4(0.f, 0.f, 0.f, 0.f);
                *(float2*)(dst + 32) = make_float2(0.f, 0.f);
            }
        }
        __syncthreads();

        for (int ic = 0; ic < ICC; ++ic) {
            const int icg = ic0 + ic;
            #pragma unroll
            for (int ky = 0; ky < 3; ++ky) {
                const float* xr = &lx[(ic * TROWS + ty + ky) * TPITCH + tx * 4];
                const float4 xa = *(const float4*)xr;         // cols 0..3
                const float2 xb = *(const float2*)(xr + 4);   // cols 4..5
                const float xv[6] = {xa.x, xa.y, xa.z, xa.w, xb.x, xb.y};
                const float* wb = &lw[(icg * 9 + ky * 3) * 8 + og * 2];
                #pragma unroll
                for (int kx = 0; kx < 3; ++kx) {
                    const float2 wv = *(const float2*)(wb + kx * 8);  // 2 oc, wave-uniform
                    const float wf[2] = {wv.x, wv.y};
                    #pragma unroll
                    for (int o = 0; o < 2; ++o)
                        #pragma unroll
                        for (int p = 0; p < 4; ++p)
                            acc[o][p] = fmaf(wf[o], xv[kx + p], acc[o][p]);
                }
            }
        }
    }

    // Bias + write batch 0 only (row pitch 126f -> 8B aligned, float2 stores)
    const int orow = row0 + ty;
    const int ocol = col0 + tx * 4;
    if (orow < OW) {
        const int nv = OW - ocol;                 // >=4 except 2 at right edge
        #pragma unroll
        for (int o = 0; o < 2; ++o) {
            const int oc = oc0 + og * 2 + o;
            const float bv = bias[oc];
            float r0 = acc[o][0] + bv, r1 = acc[o][1] + bv;
            float r2 = acc[o][2] + bv, r3 = acc[o][3] + bv;
            float* op = &out[((size_t)oc * OW + orow) * OW + ocol];
            if (nv >= 4) {
                ((float2*)op)[0] = make_float2(r0, r1);
                ((float2*)op)[1] = make_float2(r2, r3);
            } else {
                ((float2*)op)[0] = make_float2(r0, r1);
            }
        }
    }
}

// ---- Kernel 3: broadcast out[0] -> out[1..31]; nt stores, 4 f4/thread ----
// grid (31, 497): x = dst batch - 1 (fastest -> all XCDs read same src chunk),
// y = chunk of 1024 f4 (16 KB contiguous per block).
__global__ __launch_bounds__(256) void k_bcast(float* __restrict__ out) {
    const size_t dstBase = (size_t)(blockIdx.x + 1) * IMG4;
    const int r0 = blockIdx.y * 1024 + threadIdx.x;
    f4* __restrict__ o4 = (f4*)out;
    #pragma unroll
    for (int j = 0; j < 4; ++j) {
        const int r = r0 + j * 256;
        if (r < IMG4) {
            f4 v = o4[r];
            __builtin_nontemporal_store(v, &o4[dstBase + r]);
        }
    }
}

extern "C" void kernel_launch(void* const* d_in, const int* in_sizes, int n_in,
                              void* d_out, int out_size, void* d_ws, size_t ws_size,
                              hipStream_t stream) {
    const float* x    = (const float*)d_in[0];   // [32,64,128,128]
    const float* w    = (const float*)d_in[1];   // [128,64,3,3]
    const float* bias = (const float*)d_in[2];   // [128,1,1]
    float* out = (float*)d_out;                  // [32,128,126,126]
    float* xs  = (float*)d_ws;                   // [64,128,128] scratch (4 MB)

    k_bsum<<<dim3(CIN * HW * HW / 4 / 256), dim3(256), 0, stream>>>(x, xs);
    k_conv<<<dim3(64, 16), dim3(256), 0, stream>>>(xs, w, bias, out);
    k_bcast<<<dim3(BATCH - 1, (IMG4 + 1023) / 1024), dim3(256), 0, stream>>>(out);
}

// Round 6
// 122.098 us; speedup vs baseline: 2.3161x; 1.2742x over previous
//
#include <hip/hip_runtime.h>

// Problem constants: B=32, C_IN=64, C_OUT=128, K=3, H=W=128
#define BATCH 32
#define CIN   64
#define COUT  128
#define HW    128
#define OW    126            // H-K+1
#define IMG4  508032         // float4s per batch-image of out (128*126*126/4)

typedef float f4 __attribute__((ext_vector_type(4)));

// ---- Kernel 1: xs[c,h,w] = sum_b x[b,c,h,w]; f4, 4 chains, nt loads ----
__global__ __launch_bounds__(256) void k_bsum(const float* __restrict__ x,
                                              float* __restrict__ xs) {
    const int i = blockIdx.x * blockDim.x + threadIdx.x;   // over 262144 f4s
    const f4* __restrict__ x4 = (const f4*)x;
    const size_t s4 = CIN * HW * HW / 4;                   // 262144 f4 per batch
    f4 a0 = __builtin_nontemporal_load(&x4[i]);
    f4 a1 = __builtin_nontemporal_load(&x4[s4 + i]);
    f4 a2 = __builtin_nontemporal_load(&x4[2 * s4 + i]);
    f4 a3 = __builtin_nontemporal_load(&x4[3 * s4 + i]);
    #pragma unroll
    for (int b = 4; b < BATCH; b += 4) {
        a0 += __builtin_nontemporal_load(&x4[(size_t)b * s4 + i]);
        a1 += __builtin_nontemporal_load(&x4[(size_t)(b + 1) * s4 + i]);
        a2 += __builtin_nontemporal_load(&x4[(size_t)(b + 2) * s4 + i]);
        a3 += __builtin_nontemporal_load(&x4[(size_t)(b + 3) * s4 + i]);
    }
    ((f4*)xs)[i] = (a0 + a1) + (a2 + a3);
}

// ---- Kernel 2: conv(xs, w) + bias -> out batch 0 ONLY ----
// x read DIRECTLY from global (L2/L3-resident, 4 MB) into registers; only
// weights staged in LDS, consumed as wave-uniform b128 broadcasts (free).
// Tile: 8 rows x 32 cols x 16 oc. Grid (64 spatial, 8 ocg) = 512 blocks.
// Thread: tx=tid&7 (4 px), ty=(tid>>3)&7 (row), og=tid>>6 (4 oc each).
#define OCT 16             // out channels per block
#define ICC 16             // input-channel chunk for weight staging

__global__ __launch_bounds__(256, 2) void k_conv(const float* __restrict__ xs,
                                                 const float* __restrict__ w,
                                                 const float* __restrict__ bias,
                                                 float* __restrict__ out) {
    __shared__ float lw[ICC * 9 * OCT];          // 2304 floats = 9.2 KB

    const int tid  = threadIdx.x;
    const int tile = blockIdx.x;                 // 0..63
    const int ocg  = blockIdx.y;                 // 0..7
    const int row0 = (tile >> 2) * 8;            // 0..120
    const int col0 = (tile & 3) * 32;            // 0,32,64,96
    const int oc0  = ocg * OCT;

    const int tx = tid & 7;
    const int ty = (tid >> 3) & 7;
    const int og = tid >> 6;                     // 0..3 (wave-uniform)

    const int irow = row0 + ty;                  // output row; input rows irow+ky
    const int icol = col0 + tx * 4;              // output col base
    const bool tail = (icol + 5) < HW;           // cols icol+4..5 loadable

    float acc[4][4] = {};                        // [oc][px]

    for (int ic0 = 0; ic0 < CIN; ic0 += ICC) {
        __syncthreads();                         // protect lw from prior readers
        // Stage weight chunk: [(icL*9 + t)*16 + o] <- w[(oc0+o)*576 + ic0*9 + icL*9 + t]
        #pragma unroll
        for (int s = tid; s < ICC * 9 * OCT; s += 256) {
            const int o = s & 15;
            const int r = s >> 4;                // icL*9 + t
            lw[s] = w[(oc0 + o) * (CIN * 9) + ic0 * 9 + r];
        }
        __syncthreads();

        #pragma unroll 2
        for (int icL = 0; icL < ICC; ++icL) {
            const float* xb0 = &xs[(((ic0 + icL) * HW) + irow) * HW + icol];
            #pragma unroll
            for (int ky = 0; ky < 3; ++ky) {
                const int gr = irow + ky;
                float xv[6];
                if (gr < HW) {
                    const float4 xa = *(const float4*)(xb0 + ky * HW);
                    xv[0] = xa.x; xv[1] = xa.y; xv[2] = xa.z; xv[3] = xa.w;
                    if (tail) {
                        const float2 xt = *(const float2*)(xb0 + ky * HW + 4);
                        xv[4] = xt.x; xv[5] = xt.y;
                    } else { xv[4] = 0.f; xv[5] = 0.f; }
                } else {
                    xv[0] = xv[1] = xv[2] = xv[3] = xv[4] = xv[5] = 0.f;
                }
                const float* wb = &lw[(icL * 9 + ky * 3) * OCT + og * 4];
                #pragma unroll
                for (int kx = 0; kx < 3; ++kx) {
                    const float4 wv = *(const float4*)(wb + kx * OCT);  // broadcast
                    const float wf[4] = {wv.x, wv.y, wv.z, wv.w};
                    #pragma unroll
                    for (int o = 0; o < 4; ++o)
                        #pragma unroll
                        for (int p = 0; p < 4; ++p)
                            acc[o][p] = fmaf(wf[o], xv[kx + p], acc[o][p]);
                }
            }
        }
    }

    // Bias + write batch 0 only (row pitch 126f -> float2 stores)
    if (irow < OW) {
        #pragma unroll
        for (int o = 0; o < 4; ++o) {
            const int oc = oc0 + og * 4 + o;
            const float bv = bias[oc];
            const float r0 = acc[o][0] + bv, r1 = acc[o][1] + bv;
            const float r2 = acc[o][2] + bv, r3 = acc[o][3] + bv;
            float* op = &out[((size_t)oc * OW + irow) * OW + icol];
            if (icol + 4 <= OW) {
                ((float2*)op)[0] = make_float2(r0, r1);
                ((float2*)op)[1] = make_float2(r2, r3);
            } else {                              // icol == 124: 2 cols left
                ((float2*)op)[0] = make_float2(r0, r1);
            }
        }
    }
}

// ---- Kernel 3: broadcast out[0] -> out[1..31] ----
// Each block loads one 8 KB chunk (512 f4) of batch 0 into registers, then
// stores it to all 31 dst batches: 2 loads, 62 independent wide stores.
__global__ __launch_bounds__(256) void k_bcast(float* __restrict__ out) {
    f4* __restrict__ o4 = (f4*)out;
    const int r0 = blockIdx.x * 512 + threadIdx.x;
    const int r1 = r0 + 256;
    const bool ok0 = r0 < IMG4;
    const bool ok1 = r1 < IMG4;
    f4 v0 = {}; f4 v1 = {};
    if (ok0) v0 = o4[r0];
    if (ok1) v1 = o4[r1];
    #pragma unroll
    for (int b = 1; b < BATCH; ++b) {
        const size_t base = (size_t)b * IMG4;
        if (ok0) o4[base + r0] = v0;
        if (ok1) o4[base + r1] = v1;
    }
}

extern "C" void kernel_launch(void* const* d_in, const int* in_sizes, int n_in,
                              void* d_out, int out_size, void* d_ws, size_t ws_size,
                              hipStream_t stream) {
    const float* x    = (const float*)d_in[0];   // [32,64,128,128]
    const float* w    = (const float*)d_in[1];   // [128,64,3,3]
    const float* bias = (const float*)d_in[2];   // [128,1,1]
    float* out = (float*)d_out;                  // [32,128,126,126]
    float* xs  = (float*)d_ws;                   // [64,128,128] scratch (4 MB)

    k_bsum<<<dim3(CIN * HW * HW / 4 / 256), dim3(256), 0, stream>>>(x, xs);
    k_conv<<<dim3(64, 8), dim3(256), 0, stream>>>(xs, w, bias, out);
    k_bcast<<<dim3((IMG4 + 511) / 512), dim3(256), 0, stream>>>(out);
}